// Round 4
// baseline (435.879 us; speedup 1.0000x reference)
//
#include <hip/hip_runtime.h>

// GCN 2-layer forward, CSR pull-based aggregation (no float atomics).
// Layer: out[v] = dinv[v]*(hs[v] + sum_{e:dst=v} hs[src_e]) + b,  hs = (x@W)*dinv.

#define C_HID 64
#define CHUNK 1024   // elements per scan block; supports n <= 64*1024

static inline size_t alignup(size_t x) { return (x + 255) & ~(size_t)255; }

typedef __attribute__((address_space(3))) unsigned int lds_uint;
typedef __attribute__((address_space(1))) const unsigned int glob_uint;

// ---------- degree ----------
__global__ void count_deg_kernel(const int* __restrict__ dst, int E,
                                 int* __restrict__ deg) {
    int e = blockIdx.x * blockDim.x + threadIdx.x;
    if (e < E) atomicAdd(&deg[dst[e]], 1);
}

// ---------- hierarchical scan, stage A: per-block sums ----------
__global__ __launch_bounds__(CHUNK) void block_sums_kernel(
    const int* __restrict__ deg, int* __restrict__ bsum, int n) {
    __shared__ int wsum[CHUNK / 64];
    int i = blockIdx.x * CHUNK + threadIdx.x;
    int v = (i < n) ? deg[i] : 0;
#pragma unroll
    for (int off = 32; off; off >>= 1) v += __shfl_down(v, off);
    int lane = threadIdx.x & 63, wav = threadIdx.x >> 6;
    if (lane == 0) wsum[wav] = v;
    __syncthreads();
    if (threadIdx.x == 0) {
        int t = 0;
#pragma unroll
        for (int w2 = 0; w2 < CHUNK / 64; ++w2) t += wsum[w2];
        bsum[blockIdx.x] = t;
    }
}

// ---------- stage B: exclusive scan of block sums (nb <= 64, one wave) ----------
__global__ void scan_bsums_kernel(int* __restrict__ bsum, int nb) {
    int lane = threadIdx.x;
    int v = (lane < nb) ? bsum[lane] : 0;
    int s = v;
#pragma unroll
    for (int off = 1; off < 64; off <<= 1) {
        int t = __shfl_up(s, off);
        if (lane >= off) s += t;
    }
    if (lane < nb) bsum[lane] = s - v;   // exclusive prefix
}

// ---------- stage C: local scan + offset; emit row_ptr, cursor, dinv ----------
__global__ __launch_bounds__(CHUNK) void scan_chunks_kernel(
    const int* __restrict__ deg, const int* __restrict__ blkoff,
    int* __restrict__ row_ptr, int* __restrict__ cursor,
    float* __restrict__ dinv, int n) {
    __shared__ int wsum[CHUNK / 64];
    int i = blockIdx.x * CHUNK + threadIdx.x;
    int v = (i < n) ? deg[i] : 0;
    int lane = threadIdx.x & 63, wav = threadIdx.x >> 6;
    int s = v;
#pragma unroll
    for (int off = 1; off < 64; off <<= 1) {
        int t = __shfl_up(s, off);
        if (lane >= off) s += t;
    }
    if (lane == 63) wsum[wav] = s;
    __syncthreads();
    if (wav == 0) {
        int ws = (lane < CHUNK / 64) ? wsum[lane] : 0;
#pragma unroll
        for (int off = 1; off < CHUNK / 64; off <<= 1) {
            int t = __shfl_up(ws, off);
            if (lane >= off) ws += t;
        }
        if (lane < CHUNK / 64) wsum[lane] = ws;
    }
    __syncthreads();
    int base = blkoff[blockIdx.x] + (wav > 0 ? wsum[wav - 1] : 0);
    int incl = base + s;
    if (i < n) {
        row_ptr[i + 1] = incl;
        cursor[i] = incl - v;                    // exclusive prefix = bucket start
        dinv[i] = rsqrtf(1.0f + (float)v);       // +1 self-loop
    }
    if (i == 0) row_ptr[0] = 0;
}

// ---------- bucket edges by dst ----------
__global__ void place_edges_kernel(const int* __restrict__ src,
                                   const int* __restrict__ dst, int E,
                                   int* __restrict__ cursor,
                                   int* __restrict__ esrc) {
    int e = blockIdx.x * blockDim.x + threadIdx.x;
    if (e >= E) return;
    int d = dst[e];
    int pos = atomicAdd(&cursor[d], 1);
    esrc[pos] = src[e];
}

// ---------- tiled GEMM: out[r][c] = dinv[r] * sum_k X[r][k]*W[k][c] ----------
// One block per 64 rows. X tile (contiguous 64*K floats) -> LDS via
// global_load_lds width=16. Lane owns column c=lane; W column in VGPRs.
// Inner loop: broadcast ds_read_b128 of X row + v_fmac, 4 row-chains for ILP.
template <int K>
__global__ __launch_bounds__(256) void gemm_tile_kernel(
    const float* __restrict__ X, const float* __restrict__ W,
    const float* __restrict__ dinv, float* __restrict__ out, int n) {
    __shared__ float Xs[64 * K];
    const int lane = threadIdx.x & 63;
    const int wav = threadIdx.x >> 6;
    const int row0 = blockIdx.x * 64;

    // W column of this lane -> VGPRs (coalesced across lanes; W is L2-hot)
    float Wreg[K];
#pragma unroll
    for (int k = 0; k < K; ++k) Wreg[k] = W[k * 64 + lane];

    const int tile_bytes = 64 * K * 4;
    if (row0 + 64 <= n) {
        // fast path: whole tile is one contiguous in-bounds 16/32 KB block
        const char* gbase = (const char*)(X + (size_t)row0 * K);
        char* lbase = (char*)&Xs[0];
        for (int off = wav * 1024; off < tile_bytes; off += 4096) {
            __builtin_amdgcn_global_load_lds(
                (glob_uint*)(gbase + off + lane * 16),
                (lds_uint*)(lbase + off), 16, 0, 0);
        }
    } else {
        for (int i = threadIdx.x; i < 64 * K; i += 256) {
            int r = row0 + i / K;
            Xs[i] = (r < n) ? X[(size_t)r * K + (i % K)] : 0.0f;
        }
    }
    __syncthreads();   // drains vmcnt -> LDS-DMA complete

    // wave handles rows [wav*16, wav*16+16), 4 independent acc chains
    for (int r0 = wav * 16; r0 < wav * 16 + 16; r0 += 4) {
        const float4* x0 = (const float4*)&Xs[(r0 + 0) * K];
        const float4* x1 = (const float4*)&Xs[(r0 + 1) * K];
        const float4* x2 = (const float4*)&Xs[(r0 + 2) * K];
        const float4* x3 = (const float4*)&Xs[(r0 + 3) * K];
        float a0 = 0.f, a1 = 0.f, a2 = 0.f, a3 = 0.f;
#pragma unroll
        for (int k4 = 0; k4 < K / 4; ++k4) {
            float4 v0 = x0[k4], v1 = x1[k4], v2 = x2[k4], v3 = x3[k4];
            a0 = fmaf(v0.x, Wreg[4 * k4 + 0], a0);
            a0 = fmaf(v0.y, Wreg[4 * k4 + 1], a0);
            a0 = fmaf(v0.z, Wreg[4 * k4 + 2], a0);
            a0 = fmaf(v0.w, Wreg[4 * k4 + 3], a0);
            a1 = fmaf(v1.x, Wreg[4 * k4 + 0], a1);
            a1 = fmaf(v1.y, Wreg[4 * k4 + 1], a1);
            a1 = fmaf(v1.z, Wreg[4 * k4 + 2], a1);
            a1 = fmaf(v1.w, Wreg[4 * k4 + 3], a1);
            a2 = fmaf(v2.x, Wreg[4 * k4 + 0], a2);
            a2 = fmaf(v2.y, Wreg[4 * k4 + 1], a2);
            a2 = fmaf(v2.z, Wreg[4 * k4 + 2], a2);
            a2 = fmaf(v2.w, Wreg[4 * k4 + 3], a2);
            a3 = fmaf(v3.x, Wreg[4 * k4 + 0], a3);
            a3 = fmaf(v3.y, Wreg[4 * k4 + 1], a3);
            a3 = fmaf(v3.z, Wreg[4 * k4 + 2], a3);
            a3 = fmaf(v3.w, Wreg[4 * k4 + 3], a3);
        }
        int row = row0 + r0;
        if (row + 0 < n) out[(size_t)(row + 0) * 64 + lane] = a0 * dinv[row + 0];
        if (row + 1 < n) out[(size_t)(row + 1) * 64 + lane] = a1 * dinv[row + 1];
        if (row + 2 < n) out[(size_t)(row + 2) * 64 + lane] = a2 * dinv[row + 2];
        if (row + 3 < n) out[(size_t)(row + 3) * 64 + lane] = a3 * dinv[row + 3];
    }
}

// ---------- pull aggregation: one wave per node, 4 edges per inner iter ----------
template <bool RELU>
__global__ void aggregate4_kernel(const float* __restrict__ hs,
                                  const int* __restrict__ row_ptr,
                                  const int* __restrict__ esrc,
                                  const float* __restrict__ dinv,
                                  const float* __restrict__ bias,
                                  float* __restrict__ out, int n) {
    const int v = blockIdx.x * (blockDim.x >> 6) + (threadIdx.x >> 6);
    if (v >= n) return;
    const int lane = threadIdx.x & 63;
    const int sub = lane >> 4;      // 0..3: which concurrent edge
    const int c4 = lane & 15;       // float4 index within a 64-float row
    const float4* __restrict__ hs4 = (const float4*)hs;

    const int beg = row_ptr[v];
    const int end = row_ptr[v + 1];

    float4 acc = make_float4(0.f, 0.f, 0.f, 0.f);
    if (sub == 0) acc = hs4[(size_t)v * 16 + c4];   // self-loop term, once

    for (int j = beg; j < end; j += 64) {
        const int cnt = min(64, end - j);
        int eid = (j + lane < end) ? esrc[j + lane] : 0;   // coalesced edge ids
        for (int i = 0; i < cnt; i += 4) {
            int idx = i + sub;
            int s = __shfl(eid, idx < cnt ? idx : 0);
            if (idx < cnt) {
                float4 r = hs4[(size_t)s * 16 + c4];       // 4 rows x 256B per wave-iter
                acc.x += r.x; acc.y += r.y; acc.z += r.z; acc.w += r.w;
            }
        }
    }

#pragma unroll
    for (int m = 16; m < 64; m <<= 1) {
        acc.x += __shfl_xor(acc.x, m);
        acc.y += __shfl_xor(acc.y, m);
        acc.z += __shfl_xor(acc.z, m);
        acc.w += __shfl_xor(acc.w, m);
    }

    if (sub == 0) {
        float dv = dinv[v];
        float4 b4 = ((const float4*)bias)[c4];
        float4 r;
        r.x = acc.x * dv + b4.x;
        r.y = acc.y * dv + b4.y;
        r.z = acc.z * dv + b4.z;
        r.w = acc.w * dv + b4.w;
        if (RELU) {
            r.x = fmaxf(r.x, 0.f); r.y = fmaxf(r.y, 0.f);
            r.z = fmaxf(r.z, 0.f); r.w = fmaxf(r.w, 0.f);
        }
        ((float4*)out)[(size_t)v * 16 + c4] = r;
    }
}

extern "C" void kernel_launch(void* const* d_in, const int* in_sizes, int n_in,
                              void* d_out, int out_size, void* d_ws, size_t ws_size,
                              hipStream_t stream) {
    const float* x  = (const float*)d_in[0];
    const int*   ei = (const int*)d_in[1];
    const float* W1 = (const float*)d_in[2];
    const float* b1 = (const float*)d_in[3];
    const float* W2 = (const float*)d_in[4];
    const float* b2 = (const float*)d_in[5];
    float* out = (float*)d_out;

    const int C_IN = 128;
    const int n = in_sizes[0] / C_IN;   // 50000
    const int E = in_sizes[1] / 2;      // 800000
    const int* src = ei;
    const int* dst = ei + E;

    // Workspace: dinv | A | B | deg | row_ptr | cursor | bsum | esrc  (~30 MB)
    char* w = (char*)d_ws;
    float* dinv    = (float*)w; w += alignup((size_t)n * sizeof(float));
    float* A       = (float*)w; w += alignup((size_t)n * C_HID * sizeof(float));
    float* B       = (float*)w; w += alignup((size_t)n * C_HID * sizeof(float));
    int*   deg     = (int*)w;   w += alignup((size_t)n * sizeof(int));
    int*   row_ptr = (int*)w;   w += alignup((size_t)(n + 1) * sizeof(int));
    int*   cursor  = (int*)w;   w += alignup((size_t)n * sizeof(int));
    int*   bsum    = (int*)w;   w += alignup(64 * sizeof(int));
    int*   esrc    = (int*)w;

    const int TB = 256;
    const int NB = (n + CHUNK - 1) / CHUNK;   // 49 blocks (<= 64 required)

    // 1) CSR build
    hipMemsetAsync(deg, 0, (size_t)n * sizeof(int), stream);
    count_deg_kernel<<<(E + TB - 1) / TB, TB, 0, stream>>>(dst, E, deg);
    block_sums_kernel<<<NB, CHUNK, 0, stream>>>(deg, bsum, n);
    scan_bsums_kernel<<<1, 64, 0, stream>>>(bsum, NB);
    scan_chunks_kernel<<<NB, CHUNK, 0, stream>>>(deg, bsum, row_ptr, cursor, dinv, n);
    place_edges_kernel<<<(E + TB - 1) / TB, TB, 0, stream>>>(src, dst, E, cursor, esrc);

    // 2) layer 1
    gemm_tile_kernel<128><<<(n + 63) / 64, 256, 0, stream>>>(x, W1, dinv, A, n);
    aggregate4_kernel<true><<<(n + 3) / 4, 256, 0, stream>>>(A, row_ptr, esrc, dinv, b1, B, n);

    // 3) layer 2
    gemm_tile_kernel<64><<<(n + 63) / 64, 256, 0, stream>>>(B, W2, dinv, A, n);
    aggregate4_kernel<false><<<(n + 3) / 4, 256, 0, stream>>>(A, row_ptr, esrc, dinv, b2, out, n);
}

// Round 5
// 266.225 us; speedup vs baseline: 1.6373x; 1.6373x over previous
//
#include <hip/hip_runtime.h>

// GCN 2-layer forward, CSR pull-based aggregation (no float atomics).
// Layer: out[v] = dinv[v]*(hs[v] + sum_{e:dst=v} hs[src_e]) + b,  hs = (x@W)*dinv.

#define C_HID 64
#define CHUNK 1024   // elements per scan block; supports n <= 64*1024

static inline size_t alignup(size_t x) { return (x + 255) & ~(size_t)255; }

typedef __attribute__((address_space(3))) unsigned int lds_uint;
typedef __attribute__((address_space(1))) const unsigned int glob_uint;

// ---------- degree ----------
__global__ void count_deg_kernel(const int* __restrict__ dst, int E,
                                 int* __restrict__ deg) {
    int e = blockIdx.x * blockDim.x + threadIdx.x;
    if (e < E) atomicAdd(&deg[dst[e]], 1);
}

// ---------- hierarchical scan, stage A: per-block sums ----------
__global__ __launch_bounds__(CHUNK) void block_sums_kernel(
    const int* __restrict__ deg, int* __restrict__ bsum, int n) {
    __shared__ int wsum[CHUNK / 64];
    int i = blockIdx.x * CHUNK + threadIdx.x;
    int v = (i < n) ? deg[i] : 0;
#pragma unroll
    for (int off = 32; off; off >>= 1) v += __shfl_down(v, off);
    int lane = threadIdx.x & 63, wav = threadIdx.x >> 6;
    if (lane == 0) wsum[wav] = v;
    __syncthreads();
    if (threadIdx.x == 0) {
        int t = 0;
#pragma unroll
        for (int w2 = 0; w2 < CHUNK / 64; ++w2) t += wsum[w2];
        bsum[blockIdx.x] = t;
    }
}

// ---------- stage B: exclusive scan of block sums (nb <= 64, one wave) ----------
__global__ void scan_bsums_kernel(int* __restrict__ bsum, int nb) {
    int lane = threadIdx.x;
    int v = (lane < nb) ? bsum[lane] : 0;
    int s = v;
#pragma unroll
    for (int off = 1; off < 64; off <<= 1) {
        int t = __shfl_up(s, off);
        if (lane >= off) s += t;
    }
    if (lane < nb) bsum[lane] = s - v;   // exclusive prefix
}

// ---------- stage C: local scan + offset; emit row_ptr, cursor, dinv ----------
__global__ __launch_bounds__(CHUNK) void scan_chunks_kernel(
    const int* __restrict__ deg, const int* __restrict__ blkoff,
    int* __restrict__ row_ptr, int* __restrict__ cursor,
    float* __restrict__ dinv, int n) {
    __shared__ int wsum[CHUNK / 64];
    int i = blockIdx.x * CHUNK + threadIdx.x;
    int v = (i < n) ? deg[i] : 0;
    int lane = threadIdx.x & 63, wav = threadIdx.x >> 6;
    int s = v;
#pragma unroll
    for (int off = 1; off < 64; off <<= 1) {
        int t = __shfl_up(s, off);
        if (lane >= off) s += t;
    }
    if (lane == 63) wsum[wav] = s;
    __syncthreads();
    if (wav == 0) {
        int ws = (lane < CHUNK / 64) ? wsum[lane] : 0;
#pragma unroll
        for (int off = 1; off < CHUNK / 64; off <<= 1) {
            int t = __shfl_up(ws, off);
            if (lane >= off) ws += t;
        }
        if (lane < CHUNK / 64) wsum[lane] = ws;
    }
    __syncthreads();
    int base = blkoff[blockIdx.x] + (wav > 0 ? wsum[wav - 1] : 0);
    int incl = base + s;
    if (i < n) {
        row_ptr[i + 1] = incl;
        cursor[i] = incl - v;                    // exclusive prefix = bucket start
        dinv[i] = rsqrtf(1.0f + (float)v);       // +1 self-loop
    }
    if (i == 0) row_ptr[0] = 0;
}

// ---------- bucket edges by dst ----------
__global__ void place_edges_kernel(const int* __restrict__ src,
                                   const int* __restrict__ dst, int E,
                                   int* __restrict__ cursor,
                                   int* __restrict__ esrc) {
    int e = blockIdx.x * blockDim.x + threadIdx.x;
    if (e >= E) return;
    int d = dst[e];
    int pos = atomicAdd(&cursor[d], 1);
    esrc[pos] = src[e];
}

// ---------- register-tiled GEMM: out[r][c] = dinv[r]*sum_k X[r][k]*W[k][c] ----------
// Block = 256 threads -> 64x64 output tile; thread (tx,ty) owns 4x4 micro-tile.
// Ws[K][64] via global_load_lds (2-way bank alias on reads = free).
// Xs[64][K+4] (pad 4 -> compute reads 2-way = free), staged via coalesced
// dwordx4 reads + ds_write_b128.
template <int K>
__global__ __launch_bounds__(256) void gemm_rt_kernel(
    const float* __restrict__ X, const float* __restrict__ W,
    const float* __restrict__ dinv, float* __restrict__ out, int n) {
    constexpr int KP = K + 4;
    __shared__ float Xs[64 * KP];
    __shared__ float Ws[K * 64];
    const int t = threadIdx.x;
    const int lane = t & 63;
    const int wav = t >> 6;
    const int row0 = blockIdx.x * 64;

    // stage W (entire KxC_HID matrix) via LDS-DMA
    {
        const char* gb = (const char*)W;
        char* lb = (char*)Ws;
        for (int off = wav * 1024; off < K * 64 * 4; off += 4096)
            __builtin_amdgcn_global_load_lds((glob_uint*)(gb + off + lane * 16),
                                             (lds_uint*)(lb + off), 16, 0, 0);
    }
    // stage X tile: thread i -> r = i/(K/4), k0 = (i%(K/4))*4 (coalesced reads)
    if (row0 + 64 <= n) {
        const float4* g4 = (const float4*)(X + (size_t)row0 * K);
        for (int i = t; i < 64 * (K / 4); i += 256) {
            float4 v = g4[i];
            int r = i / (K / 4), k0 = (i % (K / 4)) * 4;
            *(float4*)&Xs[r * KP + k0] = v;
        }
    } else {
        for (int i = t; i < 64 * K; i += 256) {
            int r = i / K, k = i % K;
            Xs[r * KP + k] = (row0 + r < n) ? X[(size_t)(row0 + r) * K + k] : 0.0f;
        }
    }
    __syncthreads();

    const int tx = t & 15;        // cols 4tx..4tx+3
    const int ty = t >> 4;        // rows 4ty..4ty+3
    float acc[4][4] = {{0.f}};

#pragma unroll 2
    for (int k0 = 0; k0 < K; k0 += 4) {
        float4 a0 = *(const float4*)&Xs[(4 * ty + 0) * KP + k0];
        float4 a1 = *(const float4*)&Xs[(4 * ty + 1) * KP + k0];
        float4 a2 = *(const float4*)&Xs[(4 * ty + 2) * KP + k0];
        float4 a3 = *(const float4*)&Xs[(4 * ty + 3) * KP + k0];
        float4 b0 = *(const float4*)&Ws[(k0 + 0) * 64 + 4 * tx];
        float4 b1 = *(const float4*)&Ws[(k0 + 1) * 64 + 4 * tx];
        float4 b2 = *(const float4*)&Ws[(k0 + 2) * 64 + 4 * tx];
        float4 b3 = *(const float4*)&Ws[(k0 + 3) * 64 + 4 * tx];
        const float* ap[4] = {(const float*)&a0, (const float*)&a1,
                              (const float*)&a2, (const float*)&a3};
        const float* bp[4] = {(const float*)&b0, (const float*)&b1,
                              (const float*)&b2, (const float*)&b3};
#pragma unroll
        for (int r = 0; r < 4; ++r)
#pragma unroll
            for (int kk = 0; kk < 4; ++kk) {
                float av = ap[r][kk];
#pragma unroll
                for (int c = 0; c < 4; ++c)
                    acc[r][c] = fmaf(av, bp[kk][c], acc[r][c]);
            }
    }

#pragma unroll
    for (int r = 0; r < 4; ++r) {
        int row = row0 + 4 * ty + r;
        if (row < n) {
            float dv = dinv[row];
            float4 o = make_float4(acc[r][0] * dv, acc[r][1] * dv,
                                   acc[r][2] * dv, acc[r][3] * dv);
            *(float4*)&out[(size_t)row * 64 + 4 * tx] = o;
        }
    }
}

// ---------- pull aggregation: one wave per node, 4 edges per inner iter ----------
template <bool RELU>
__global__ void aggregate4_kernel(const float* __restrict__ hs,
                                  const int* __restrict__ row_ptr,
                                  const int* __restrict__ esrc,
                                  const float* __restrict__ dinv,
                                  const float* __restrict__ bias,
                                  float* __restrict__ out, int n) {
    const int v = blockIdx.x * (blockDim.x >> 6) + (threadIdx.x >> 6);
    if (v >= n) return;
    const int lane = threadIdx.x & 63;
    const int sub = lane >> 4;      // 0..3: which concurrent edge
    const int c4 = lane & 15;       // float4 index within a 64-float row
    const float4* __restrict__ hs4 = (const float4*)hs;

    const int beg = row_ptr[v];
    const int end = row_ptr[v + 1];

    float4 acc = make_float4(0.f, 0.f, 0.f, 0.f);
    if (sub == 0) acc = hs4[(size_t)v * 16 + c4];   // self-loop term, once

    for (int j = beg; j < end; j += 64) {
        const int cnt = min(64, end - j);
        int eid = (j + lane < end) ? esrc[j + lane] : 0;   // coalesced edge ids
        for (int i = 0; i < cnt; i += 4) {
            int idx = i + sub;
            int s = __shfl(eid, idx < cnt ? idx : 0);
            if (idx < cnt) {
                float4 r = hs4[(size_t)s * 16 + c4];       // 4 rows x 256B per wave-iter
                acc.x += r.x; acc.y += r.y; acc.z += r.z; acc.w += r.w;
            }
        }
    }

#pragma unroll
    for (int m = 16; m < 64; m <<= 1) {
        acc.x += __shfl_xor(acc.x, m);
        acc.y += __shfl_xor(acc.y, m);
        acc.z += __shfl_xor(acc.z, m);
        acc.w += __shfl_xor(acc.w, m);
    }

    if (sub == 0) {
        float dv = dinv[v];
        float4 b4 = ((const float4*)bias)[c4];
        float4 r;
        r.x = acc.x * dv + b4.x;
        r.y = acc.y * dv + b4.y;
        r.z = acc.z * dv + b4.z;
        r.w = acc.w * dv + b4.w;
        if (RELU) {
            r.x = fmaxf(r.x, 0.f); r.y = fmaxf(r.y, 0.f);
            r.z = fmaxf(r.z, 0.f); r.w = fmaxf(r.w, 0.f);
        }
        ((float4*)out)[(size_t)v * 16 + c4] = r;
    }
}

extern "C" void kernel_launch(void* const* d_in, const int* in_sizes, int n_in,
                              void* d_out, int out_size, void* d_ws, size_t ws_size,
                              hipStream_t stream) {
    const float* x  = (const float*)d_in[0];
    const int*   ei = (const int*)d_in[1];
    const float* W1 = (const float*)d_in[2];
    const float* b1 = (const float*)d_in[3];
    const float* W2 = (const float*)d_in[4];
    const float* b2 = (const float*)d_in[5];
    float* out = (float*)d_out;

    const int C_IN = 128;
    const int n = in_sizes[0] / C_IN;   // 50000
    const int E = in_sizes[1] / 2;      // 800000
    const int* src = ei;
    const int* dst = ei + E;

    // Workspace: dinv | A | B | deg | row_ptr | cursor | bsum | esrc  (~30 MB)
    char* w = (char*)d_ws;
    float* dinv    = (float*)w; w += alignup((size_t)n * sizeof(float));
    float* A       = (float*)w; w += alignup((size_t)n * C_HID * sizeof(float));
    float* B       = (float*)w; w += alignup((size_t)n * C_HID * sizeof(float));
    int*   deg     = (int*)w;   w += alignup((size_t)n * sizeof(int));
    int*   row_ptr = (int*)w;   w += alignup((size_t)(n + 1) * sizeof(int));
    int*   cursor  = (int*)w;   w += alignup((size_t)n * sizeof(int));
    int*   bsum    = (int*)w;   w += alignup(64 * sizeof(int));
    int*   esrc    = (int*)w;

    const int TB = 256;
    const int NB = (n + CHUNK - 1) / CHUNK;   // 49 blocks (<= 64 required)

    // 1) CSR build
    hipMemsetAsync(deg, 0, (size_t)n * sizeof(int), stream);
    count_deg_kernel<<<(E + TB - 1) / TB, TB, 0, stream>>>(dst, E, deg);
    block_sums_kernel<<<NB, CHUNK, 0, stream>>>(deg, bsum, n);
    scan_bsums_kernel<<<1, 64, 0, stream>>>(bsum, NB);
    scan_chunks_kernel<<<NB, CHUNK, 0, stream>>>(deg, bsum, row_ptr, cursor, dinv, n);
    place_edges_kernel<<<(E + TB - 1) / TB, TB, 0, stream>>>(src, dst, E, cursor, esrc);

    // 2) layer 1
    gemm_rt_kernel<128><<<(n + 63) / 64, 256, 0, stream>>>(x, W1, dinv, A, n);
    aggregate4_kernel<true><<<(n + 3) / 4, 256, 0, stream>>>(A, row_ptr, esrc, dinv, b1, B, n);

    // 3) layer 2
    gemm_rt_kernel<64><<<(n + 63) / 64, 256, 0, stream>>>(B, W2, dinv, A, n);
    aggregate4_kernel<false><<<(n + 3) / 4, 256, 0, stream>>>(A, row_ptr, esrc, dinv, b2, out, n);
}

// Round 6
// 216.435 us; speedup vs baseline: 2.0139x; 1.2300x over previous
//
#include <hip/hip_runtime.h>

// GCN 2-layer forward. CSR built via deterministic 2-level bucket sort
// (bucket = dst>>10, 1024 nodes/bucket); pull-based aggregation, no global
// atomics anywhere.
// Layer: out[v] = dinv[v]*(hs[v] + sum_{e:dst=v} hs[src_e]) + b,  hs = (x@W)*dinv.

#define C_HID 64
#define NBLK 128          // blocks for hist/scatter passes

static inline size_t alignup(size_t x) { return (x + 255) & ~(size_t)255; }

typedef __attribute__((address_space(3))) unsigned int lds_uint;
typedef __attribute__((address_space(1))) const unsigned int glob_uint;

// ---------- pass A: per-(block,bucket) histogram ----------
__global__ __launch_bounds__(256) void hist_kernel(
    const int* __restrict__ dst, int E, int ePer,
    int* __restrict__ S, int nbuck) {
    __shared__ int h[64];
    for (int i = threadIdx.x; i < nbuck; i += 256) h[i] = 0;
    __syncthreads();
    int beg = blockIdx.x * ePer, end = min(E, beg + ePer);
    for (int e = beg + threadIdx.x; e < end; e += 256)
        atomicAdd(&h[dst[e] >> 10], 1);
    __syncthreads();
    for (int b = threadIdx.x; b < nbuck; b += 256)
        S[b * NBLK + blockIdx.x] = h[b];
}

// ---------- pass B: exclusive scan of S (bucket-major), in place ----------
__global__ __launch_bounds__(1024) void scan_hist_kernel(int* __restrict__ S, int m) {
    __shared__ int wsum[16];
    int carry = 0;
    const int lane = threadIdx.x & 63, wav = threadIdx.x >> 6;
    for (int base = 0; base < m; base += 1024) {
        int i = base + threadIdx.x;
        int v = (i < m) ? S[i] : 0;
        int s = v;
#pragma unroll
        for (int off = 1; off < 64; off <<= 1) {
            int t = __shfl_up(s, off);
            if (lane >= off) s += t;
        }
        if (lane == 63) wsum[wav] = s;
        __syncthreads();
        if (wav == 0 && lane < 16) {
            int ws = wsum[lane];
#pragma unroll
            for (int off = 1; off < 16; off <<= 1) {
                int t = __shfl_up(ws, off);
                if (lane >= off) ws += t;
            }
            wsum[lane] = ws;
        }
        __syncthreads();
        int chunk_total = wsum[15];
        int excl = carry + (wav ? wsum[wav - 1] : 0) + (s - v);
        if (i < m) S[i] = excl;
        carry += chunk_total;
        __syncthreads();   // protect wsum before next chunk
    }
}

// ---------- pass C: scatter edges into bucket-grouped runs ----------
// Block i's edges for bucket b land contiguously at S[b*NBLK+i] -> dense writes.
__global__ __launch_bounds__(256) void bucket_scatter_kernel(
    const int* __restrict__ src, const int* __restrict__ dst, int E, int ePer,
    const int* __restrict__ S, unsigned* __restrict__ ebuf, int nbuck) {
    __shared__ int cur[64];
    int beg = blockIdx.x * ePer, end = min(E, beg + ePer);
    for (int i = threadIdx.x; i < nbuck; i += 256)
        cur[i] = S[i * NBLK + blockIdx.x];
    __syncthreads();
    for (int e = beg + threadIdx.x; e < end; e += 256) {
        int d = dst[e];
        int s = src[e];
        int pos = atomicAdd(&cur[d >> 10], 1);            // LDS atomic
        ebuf[pos] = ((unsigned)s << 10) | (unsigned)(d & 1023);
    }
}

// ---------- pass D: per-bucket CSR finalize ----------
// One 1024-thread block per bucket: LDS degree hist -> LDS scan -> row_ptr,
// dinv (coalesced), then scatter esrc with LDS cursors into this bucket's
// contiguous CSR segment (single-XCD L2 region -> dense writeback).
__global__ __launch_bounds__(1024) void build_csr_kernel(
    const unsigned* __restrict__ ebuf, const int* __restrict__ S,
    int* __restrict__ row_ptr, float* __restrict__ dinv,
    int* __restrict__ esrc, int n, int nbuck, int E) {
    __shared__ int hist[1024];
    __shared__ int wsum[16];
    const int b = blockIdx.x;
    const int node0 = b << 10;
    const int ebeg = S[b * NBLK];
    const int eend = (b + 1 < nbuck) ? S[(b + 1) * NBLK] : E;
    const int lane = threadIdx.x & 63, wav = threadIdx.x >> 6;

    hist[threadIdx.x] = 0;
    __syncthreads();
    for (int e = ebeg + threadIdx.x; e < eend; e += 1024)
        atomicAdd(&hist[ebuf[e] & 1023], 1);
    __syncthreads();
    int deg = hist[threadIdx.x];

    // block-wide inclusive scan of deg (16 waves)
    int s = deg;
#pragma unroll
    for (int off = 1; off < 64; off <<= 1) {
        int t = __shfl_up(s, off);
        if (lane >= off) s += t;
    }
    if (lane == 63) wsum[wav] = s;
    __syncthreads();
    if (wav == 0 && lane < 16) {
        int ws = wsum[lane];
#pragma unroll
        for (int off = 1; off < 16; off <<= 1) {
            int t = __shfl_up(ws, off);
            if (lane >= off) ws += t;
        }
        wsum[lane] = ws;
    }
    __syncthreads();
    int incl = (wav ? wsum[wav - 1] : 0) + s;
    int excl = incl - deg;
    __syncthreads();
    hist[threadIdx.x] = ebeg + excl;   // cursor for this local node
    int v = node0 + threadIdx.x;
    if (v < n) {
        row_ptr[v + 1] = ebeg + incl;
        dinv[v] = rsqrtf(1.0f + (float)deg);
        if (v == 0) row_ptr[0] = 0;
    }
    __syncthreads();
    for (int e = ebeg + threadIdx.x; e < eend; e += 1024) {
        unsigned p = ebuf[e];
        int pos = atomicAdd(&hist[p & 1023], 1);          // LDS atomic
        esrc[pos] = (int)(p >> 10);
    }
}

// ---------- register-tiled GEMM: out[r][c] = dinv[r]*sum_k X[r][k]*W[k][c] ----------
template <int K>
__global__ __launch_bounds__(256) void gemm_rt_kernel(
    const float* __restrict__ X, const float* __restrict__ W,
    const float* __restrict__ dinv, float* __restrict__ out, int n) {
    constexpr int KP = K + 4;
    __shared__ float Xs[64 * KP];
    __shared__ float Ws[K * 64];
    const int t = threadIdx.x;
    const int lane = t & 63;
    const int wav = t >> 6;
    const int row0 = blockIdx.x * 64;

    {
        const char* gb = (const char*)W;
        char* lb = (char*)Ws;
        for (int off = wav * 1024; off < K * 64 * 4; off += 4096)
            __builtin_amdgcn_global_load_lds((glob_uint*)(gb + off + lane * 16),
                                             (lds_uint*)(lb + off), 16, 0, 0);
    }
    if (row0 + 64 <= n) {
        const float4* g4 = (const float4*)(X + (size_t)row0 * K);
        for (int i = t; i < 64 * (K / 4); i += 256) {
            float4 v = g4[i];
            int r = i / (K / 4), k0 = (i % (K / 4)) * 4;
            *(float4*)&Xs[r * KP + k0] = v;
        }
    } else {
        for (int i = t; i < 64 * K; i += 256) {
            int r = i / K, k = i % K;
            Xs[r * KP + k] = (row0 + r < n) ? X[(size_t)(row0 + r) * K + k] : 0.0f;
        }
    }
    __syncthreads();

    const int tx = t & 15;
    const int ty = t >> 4;
    float acc[4][4] = {{0.f}};

#pragma unroll 2
    for (int k0 = 0; k0 < K; k0 += 4) {
        float4 a0 = *(const float4*)&Xs[(4 * ty + 0) * KP + k0];
        float4 a1 = *(const float4*)&Xs[(4 * ty + 1) * KP + k0];
        float4 a2 = *(const float4*)&Xs[(4 * ty + 2) * KP + k0];
        float4 a3 = *(const float4*)&Xs[(4 * ty + 3) * KP + k0];
        float4 b0 = *(const float4*)&Ws[(k0 + 0) * 64 + 4 * tx];
        float4 b1 = *(const float4*)&Ws[(k0 + 1) * 64 + 4 * tx];
        float4 b2 = *(const float4*)&Ws[(k0 + 2) * 64 + 4 * tx];
        float4 b3 = *(const float4*)&Ws[(k0 + 3) * 64 + 4 * tx];
        const float* ap[4] = {(const float*)&a0, (const float*)&a1,
                              (const float*)&a2, (const float*)&a3};
        const float* bp[4] = {(const float*)&b0, (const float*)&b1,
                              (const float*)&b2, (const float*)&b3};
#pragma unroll
        for (int r = 0; r < 4; ++r)
#pragma unroll
            for (int kk = 0; kk < 4; ++kk) {
                float av = ap[r][kk];
#pragma unroll
                for (int c = 0; c < 4; ++c)
                    acc[r][c] = fmaf(av, bp[kk][c], acc[r][c]);
            }
    }

#pragma unroll
    for (int r = 0; r < 4; ++r) {
        int row = row0 + 4 * ty + r;
        if (row < n) {
            float dv = dinv[row];
            float4 o = make_float4(acc[r][0] * dv, acc[r][1] * dv,
                                   acc[r][2] * dv, acc[r][3] * dv);
            *(float4*)&out[(size_t)row * 64 + 4 * tx] = o;
        }
    }
}

// ---------- pull aggregation: one wave per node, 4 edges per inner iter ----------
template <bool RELU>
__global__ void aggregate4_kernel(const float* __restrict__ hs,
                                  const int* __restrict__ row_ptr,
                                  const int* __restrict__ esrc,
                                  const float* __restrict__ dinv,
                                  const float* __restrict__ bias,
                                  float* __restrict__ out, int n) {
    const int v = blockIdx.x * (blockDim.x >> 6) + (threadIdx.x >> 6);
    if (v >= n) return;
    const int lane = threadIdx.x & 63;
    const int sub = lane >> 4;
    const int c4 = lane & 15;
    const float4* __restrict__ hs4 = (const float4*)hs;

    const int beg = row_ptr[v];
    const int end = row_ptr[v + 1];

    float4 acc = make_float4(0.f, 0.f, 0.f, 0.f);
    if (sub == 0) acc = hs4[(size_t)v * 16 + c4];   // self-loop term

    for (int j = beg; j < end; j += 64) {
        const int cnt = min(64, end - j);
        int eid = (j + lane < end) ? esrc[j + lane] : 0;
        for (int i = 0; i < cnt; i += 4) {
            int idx = i + sub;
            int s = __shfl(eid, idx < cnt ? idx : 0);
            if (idx < cnt) {
                float4 r = hs4[(size_t)s * 16 + c4];
                acc.x += r.x; acc.y += r.y; acc.z += r.z; acc.w += r.w;
            }
        }
    }

#pragma unroll
    for (int m = 16; m < 64; m <<= 1) {
        acc.x += __shfl_xor(acc.x, m);
        acc.y += __shfl_xor(acc.y, m);
        acc.z += __shfl_xor(acc.z, m);
        acc.w += __shfl_xor(acc.w, m);
    }

    if (sub == 0) {
        float dv = dinv[v];
        float4 b4 = ((const float4*)bias)[c4];
        float4 r;
        r.x = acc.x * dv + b4.x;
        r.y = acc.y * dv + b4.y;
        r.z = acc.z * dv + b4.z;
        r.w = acc.w * dv + b4.w;
        if (RELU) {
            r.x = fmaxf(r.x, 0.f); r.y = fmaxf(r.y, 0.f);
            r.z = fmaxf(r.z, 0.f); r.w = fmaxf(r.w, 0.f);
        }
        ((float4*)out)[(size_t)v * 16 + c4] = r;
    }
}

extern "C" void kernel_launch(void* const* d_in, const int* in_sizes, int n_in,
                              void* d_out, int out_size, void* d_ws, size_t ws_size,
                              hipStream_t stream) {
    const float* x  = (const float*)d_in[0];
    const int*   ei = (const int*)d_in[1];
    const float* W1 = (const float*)d_in[2];
    const float* b1 = (const float*)d_in[3];
    const float* W2 = (const float*)d_in[4];
    const float* b2 = (const float*)d_in[5];
    float* out = (float*)d_out;

    const int C_IN = 128;
    const int n = in_sizes[0] / C_IN;   // 50000
    const int E = in_sizes[1] / 2;      // 800000
    const int* src = ei;
    const int* dst = ei + E;

    // Workspace: dinv | A | B | row_ptr | S | ebuf | esrc  (~33 MB)
    char* w = (char*)d_ws;
    float*    dinv    = (float*)w;    w += alignup((size_t)n * sizeof(float));
    float*    A       = (float*)w;    w += alignup((size_t)n * C_HID * sizeof(float));
    float*    B       = (float*)w;    w += alignup((size_t)n * C_HID * sizeof(float));
    int*      row_ptr = (int*)w;      w += alignup((size_t)(n + 1) * sizeof(int));
    int*      S       = (int*)w;      w += alignup((size_t)64 * NBLK * sizeof(int));
    unsigned* ebuf    = (unsigned*)w; w += alignup((size_t)E * sizeof(unsigned));
    int*      esrc    = (int*)w;

    const int NB2 = (n + 1023) >> 10;           // 49 buckets (needs n <= 65536)
    const int ePer = (E + NBLK - 1) / NBLK;     // 6250 edges per block

    // 1) CSR build (no global atomics)
    hist_kernel<<<NBLK, 256, 0, stream>>>(dst, E, ePer, S, NB2);
    scan_hist_kernel<<<1, 1024, 0, stream>>>(S, NB2 * NBLK);
    bucket_scatter_kernel<<<NBLK, 256, 0, stream>>>(src, dst, E, ePer, S, ebuf, NB2);
    build_csr_kernel<<<NB2, 1024, 0, stream>>>(ebuf, S, row_ptr, dinv, esrc, n, NB2, E);

    // 2) layer 1
    gemm_rt_kernel<128><<<(n + 63) / 64, 256, 0, stream>>>(x, W1, dinv, A, n);
    aggregate4_kernel<true><<<(n + 3) / 4, 256, 0, stream>>>(A, row_ptr, esrc, dinv, b1, B, n);

    // 3) layer 2
    gemm_rt_kernel<64><<<(n + 63) / 64, 256, 0, stream>>>(B, W2, dinv, A, n);
    aggregate4_kernel<false><<<(n + 3) / 4, 256, 0, stream>>>(A, row_ptr, esrc, dinv, b2, out, n);
}

// Round 7
// 200.079 us; speedup vs baseline: 2.1785x; 1.0817x over previous
//
#include <hip/hip_runtime.h>
#include <hip/hip_fp16.h>

// GCN 2-layer forward. CSR via deterministic 2-level bucket sort (no global
// atomics); pull-based aggregation gathering fp16 hs rows (fp32 accumulate).
// Layer: out[v] = dinv[v]*(hs[v] + sum_{e:dst=v} hs[src_e]) + b,  hs = (x@W)*dinv.

#define C_HID 64
#define NBLK 128          // blocks for hist/scatter passes

static inline size_t alignup(size_t x) { return (x + 255) & ~(size_t)255; }

typedef __attribute__((address_space(3))) unsigned int lds_uint;
typedef __attribute__((address_space(1))) const unsigned int glob_uint;

// ---------- pass A: per-(block,bucket) histogram ----------
__global__ __launch_bounds__(256) void hist_kernel(
    const int* __restrict__ dst, int E, int ePer,
    int* __restrict__ S, int nbuck) {
    __shared__ int h[64];
    for (int i = threadIdx.x; i < nbuck; i += 256) h[i] = 0;
    __syncthreads();
    int beg = blockIdx.x * ePer, end = min(E, beg + ePer);
    for (int e = beg + threadIdx.x; e < end; e += 256)
        atomicAdd(&h[dst[e] >> 10], 1);
    __syncthreads();
    for (int b = threadIdx.x; b < nbuck; b += 256)
        S[b * NBLK + blockIdx.x] = h[b];
}

// ---------- pass B: exclusive scan of S (bucket-major), in place ----------
__global__ __launch_bounds__(1024) void scan_hist_kernel(int* __restrict__ S, int m) {
    __shared__ int wsum[16];
    int carry = 0;
    const int lane = threadIdx.x & 63, wav = threadIdx.x >> 6;
    for (int base = 0; base < m; base += 1024) {
        int i = base + threadIdx.x;
        int v = (i < m) ? S[i] : 0;
        int s = v;
#pragma unroll
        for (int off = 1; off < 64; off <<= 1) {
            int t = __shfl_up(s, off);
            if (lane >= off) s += t;
        }
        if (lane == 63) wsum[wav] = s;
        __syncthreads();
        if (wav == 0 && lane < 16) {
            int ws = wsum[lane];
#pragma unroll
            for (int off = 1; off < 16; off <<= 1) {
                int t = __shfl_up(ws, off);
                if (lane >= off) ws += t;
            }
            wsum[lane] = ws;
        }
        __syncthreads();
        int chunk_total = wsum[15];
        int excl = carry + (wav ? wsum[wav - 1] : 0) + (s - v);
        if (i < m) S[i] = excl;
        carry += chunk_total;
        __syncthreads();
    }
}

// ---------- pass C: scatter edges into bucket-grouped runs ----------
__global__ __launch_bounds__(256) void bucket_scatter_kernel(
    const int* __restrict__ src, const int* __restrict__ dst, int E, int ePer,
    const int* __restrict__ S, unsigned* __restrict__ ebuf, int nbuck) {
    __shared__ int cur[64];
    int beg = blockIdx.x * ePer, end = min(E, beg + ePer);
    for (int i = threadIdx.x; i < nbuck; i += 256)
        cur[i] = S[i * NBLK + blockIdx.x];
    __syncthreads();
    for (int e = beg + threadIdx.x; e < end; e += 256) {
        int d = dst[e];
        int s = src[e];
        int pos = atomicAdd(&cur[d >> 10], 1);            // LDS atomic
        ebuf[pos] = ((unsigned)s << 10) | (unsigned)(d & 1023);
    }
}

// ---------- pass D: per-bucket CSR finalize ----------
__global__ __launch_bounds__(1024) void build_csr_kernel(
    const unsigned* __restrict__ ebuf, const int* __restrict__ S,
    int* __restrict__ row_ptr, float* __restrict__ dinv,
    int* __restrict__ esrc, int n, int nbuck, int E) {
    __shared__ int hist[1024];
    __shared__ int wsum[16];
    const int b = blockIdx.x;
    const int node0 = b << 10;
    const int ebeg = S[b * NBLK];
    const int eend = (b + 1 < nbuck) ? S[(b + 1) * NBLK] : E;
    const int lane = threadIdx.x & 63, wav = threadIdx.x >> 6;

    hist[threadIdx.x] = 0;
    __syncthreads();
    for (int e = ebeg + threadIdx.x; e < eend; e += 1024)
        atomicAdd(&hist[ebuf[e] & 1023], 1);
    __syncthreads();
    int deg = hist[threadIdx.x];

    int s = deg;
#pragma unroll
    for (int off = 1; off < 64; off <<= 1) {
        int t = __shfl_up(s, off);
        if (lane >= off) s += t;
    }
    if (lane == 63) wsum[wav] = s;
    __syncthreads();
    if (wav == 0 && lane < 16) {
        int ws = wsum[lane];
#pragma unroll
        for (int off = 1; off < 16; off <<= 1) {
            int t = __shfl_up(ws, off);
            if (lane >= off) ws += t;
        }
        wsum[lane] = ws;
    }
    __syncthreads();
    int incl = (wav ? wsum[wav - 1] : 0) + s;
    int excl = incl - deg;
    __syncthreads();
    hist[threadIdx.x] = ebeg + excl;
    int v = node0 + threadIdx.x;
    if (v < n) {
        row_ptr[v + 1] = ebeg + incl;
        dinv[v] = rsqrtf(1.0f + (float)deg);
        if (v == 0) row_ptr[0] = 0;
    }
    __syncthreads();
    for (int e = ebeg + threadIdx.x; e < eend; e += 1024) {
        unsigned p = ebuf[e];
        int pos = atomicAdd(&hist[p & 1023], 1);          // LDS atomic
        esrc[pos] = (int)(p >> 10);
    }
}

// ---------- register-tiled GEMM, fp16 output: outh[r][c] = half(dinv[r]*sum_k X[r][k]*W[k][c]) ----------
template <int K>
__global__ __launch_bounds__(256) void gemm_rt_h_kernel(
    const float* __restrict__ X, const float* __restrict__ W,
    const float* __restrict__ dinv, __half* __restrict__ outh, int n) {
    constexpr int KP = K + 4;
    __shared__ float Xs[64 * KP];
    __shared__ float Ws[K * 64];
    const int t = threadIdx.x;
    const int lane = t & 63;
    const int wav = t >> 6;
    const int row0 = blockIdx.x * 64;

    {
        const char* gb = (const char*)W;
        char* lb = (char*)Ws;
        for (int off = wav * 1024; off < K * 64 * 4; off += 4096)
            __builtin_amdgcn_global_load_lds((glob_uint*)(gb + off + lane * 16),
                                             (lds_uint*)(lb + off), 16, 0, 0);
    }
    if (row0 + 64 <= n) {
        const float4* g4 = (const float4*)(X + (size_t)row0 * K);
        for (int i = t; i < 64 * (K / 4); i += 256) {
            float4 v = g4[i];
            int r = i / (K / 4), k0 = (i % (K / 4)) * 4;
            *(float4*)&Xs[r * KP + k0] = v;
        }
    } else {
        for (int i = t; i < 64 * K; i += 256) {
            int r = i / K, k = i % K;
            Xs[r * KP + k] = (row0 + r < n) ? X[(size_t)(row0 + r) * K + k] : 0.0f;
        }
    }
    __syncthreads();

    const int tx = t & 15;
    const int ty = t >> 4;
    float acc[4][4] = {{0.f}};

#pragma unroll 2
    for (int k0 = 0; k0 < K; k0 += 4) {
        float4 a0 = *(const float4*)&Xs[(4 * ty + 0) * KP + k0];
        float4 a1 = *(const float4*)&Xs[(4 * ty + 1) * KP + k0];
        float4 a2 = *(const float4*)&Xs[(4 * ty + 2) * KP + k0];
        float4 a3 = *(const float4*)&Xs[(4 * ty + 3) * KP + k0];
        float4 b0 = *(const float4*)&Ws[(k0 + 0) * 64 + 4 * tx];
        float4 b1 = *(const float4*)&Ws[(k0 + 1) * 64 + 4 * tx];
        float4 b2 = *(const float4*)&Ws[(k0 + 2) * 64 + 4 * tx];
        float4 b3 = *(const float4*)&Ws[(k0 + 3) * 64 + 4 * tx];
        const float* ap[4] = {(const float*)&a0, (const float*)&a1,
                              (const float*)&a2, (const float*)&a3};
        const float* bp[4] = {(const float*)&b0, (const float*)&b1,
                              (const float*)&b2, (const float*)&b3};
#pragma unroll
        for (int r = 0; r < 4; ++r)
#pragma unroll
            for (int kk = 0; kk < 4; ++kk) {
                float av = ap[r][kk];
#pragma unroll
                for (int c = 0; c < 4; ++c)
                    acc[r][c] = fmaf(av, bp[kk][c], acc[r][c]);
            }
    }

#pragma unroll
    for (int r = 0; r < 4; ++r) {
        int row = row0 + 4 * ty + r;
        if (row < n) {
            float dv = dinv[row];
            __half2 p01 = __floats2half2_rn(acc[r][0] * dv, acc[r][1] * dv);
            __half2 p23 = __floats2half2_rn(acc[r][2] * dv, acc[r][3] * dv);
            float2 st;
            ((__half2*)&st)[0] = p01;
            ((__half2*)&st)[1] = p23;
            *(float2*)&outh[(size_t)row * 64 + 4 * tx] = st;   // 8B, coalesced per row
        }
    }
}

// ---------- pull aggregation: one wave per node, 8 edges per inner iter ----------
// lane -> sub = lane>>3 (which edge), c8 = lane&7 (16B = 8 fp16 channels).
template <bool RELU>
__global__ void aggregate8h_kernel(const __half* __restrict__ hs,
                                   const int* __restrict__ row_ptr,
                                   const int* __restrict__ esrc,
                                   const float* __restrict__ dinv,
                                   const float* __restrict__ bias,
                                   float* __restrict__ out, int n) {
    const int v = blockIdx.x * (blockDim.x >> 6) + (threadIdx.x >> 6);
    if (v >= n) return;
    const int lane = threadIdx.x & 63;
    const int sub = lane >> 3;      // 0..7: which concurrent edge
    const int c8 = lane & 7;        // which 16B chunk of the 128B fp16 row
    const float4* __restrict__ hs4 = (const float4*)hs;   // row = 8 float4s

    const int beg = row_ptr[v];
    const int end = row_ptr[v + 1];

    float acc[8] = {0.f};
    if (sub == 0) {                 // self-loop term, once
        float4 raw = hs4[(size_t)v * 8 + c8];
        const __half2* hp = (const __half2*)&raw;
#pragma unroll
        for (int q = 0; q < 4; ++q) {
            float2 f = __half22float2(hp[q]);
            acc[2 * q] += f.x; acc[2 * q + 1] += f.y;
        }
    }

    for (int j = beg; j < end; j += 64) {
        const int cnt = min(64, end - j);
        int eid = (j + lane < end) ? esrc[j + lane] : 0;   // coalesced edge ids
        for (int i = 0; i < cnt; i += 8) {
            int idx = i + sub;
            int s = __shfl(eid, idx < cnt ? idx : 0);
            if (idx < cnt) {
                float4 raw = hs4[(size_t)s * 8 + c8];      // 8 rows x 128B per wave-iter
                const __half2* hp = (const __half2*)&raw;
#pragma unroll
                for (int q = 0; q < 4; ++q) {
                    float2 f = __half22float2(hp[q]);
                    acc[2 * q] += f.x; acc[2 * q + 1] += f.y;
                }
            }
        }
    }

    // reduce the 8 sub-accumulators (lanes differing in bits 3-5)
#pragma unroll
    for (int m = 8; m < 64; m <<= 1)
#pragma unroll
        for (int q = 0; q < 8; ++q) acc[q] += __shfl_xor(acc[q], m);

    if (sub == 0) {
        float dv = dinv[v];
        const float* bp = bias + c8 * 8;
        float4 o0, o1;
        o0.x = acc[0] * dv + bp[0]; o0.y = acc[1] * dv + bp[1];
        o0.z = acc[2] * dv + bp[2]; o0.w = acc[3] * dv + bp[3];
        o1.x = acc[4] * dv + bp[4]; o1.y = acc[5] * dv + bp[5];
        o1.z = acc[6] * dv + bp[6]; o1.w = acc[7] * dv + bp[7];
        if (RELU) {
            o0.x = fmaxf(o0.x, 0.f); o0.y = fmaxf(o0.y, 0.f);
            o0.z = fmaxf(o0.z, 0.f); o0.w = fmaxf(o0.w, 0.f);
            o1.x = fmaxf(o1.x, 0.f); o1.y = fmaxf(o1.y, 0.f);
            o1.z = fmaxf(o1.z, 0.f); o1.w = fmaxf(o1.w, 0.f);
        }
        float4* op = (float4*)(out + (size_t)v * 64 + c8 * 8);
        op[0] = o0;
        op[1] = o1;
    }
}

extern "C" void kernel_launch(void* const* d_in, const int* in_sizes, int n_in,
                              void* d_out, int out_size, void* d_ws, size_t ws_size,
                              hipStream_t stream) {
    const float* x  = (const float*)d_in[0];
    const int*   ei = (const int*)d_in[1];
    const float* W1 = (const float*)d_in[2];
    const float* b1 = (const float*)d_in[3];
    const float* W2 = (const float*)d_in[4];
    const float* b2 = (const float*)d_in[5];
    float* out = (float*)d_out;

    const int C_IN = 128;
    const int n = in_sizes[0] / C_IN;   // 50000
    const int E = in_sizes[1] / 2;      // 800000
    const int* src = ei;
    const int* dst = ei + E;

    // Workspace: dinv | Ah (fp16) | B (f32) | row_ptr | S | ebuf | esrc  (~27 MB)
    char* w = (char*)d_ws;
    float*    dinv    = (float*)w;    w += alignup((size_t)n * sizeof(float));
    __half*   Ah      = (__half*)w;   w += alignup((size_t)n * C_HID * sizeof(__half));
    float*    B       = (float*)w;    w += alignup((size_t)n * C_HID * sizeof(float));
    int*      row_ptr = (int*)w;      w += alignup((size_t)(n + 1) * sizeof(int));
    int*      S       = (int*)w;      w += alignup((size_t)64 * NBLK * sizeof(int));
    unsigned* ebuf    = (unsigned*)w; w += alignup((size_t)E * sizeof(unsigned));
    int*      esrc    = (int*)w;

    const int NB2 = (n + 1023) >> 10;           // 49 buckets (needs n <= 65536)
    const int ePer = (E + NBLK - 1) / NBLK;     // edges per block

    // 1) CSR build (no global atomics)
    hist_kernel<<<NBLK, 256, 0, stream>>>(dst, E, ePer, S, NB2);
    scan_hist_kernel<<<1, 1024, 0, stream>>>(S, NB2 * NBLK);
    bucket_scatter_kernel<<<NBLK, 256, 0, stream>>>(src, dst, E, ePer, S, ebuf, NB2);
    build_csr_kernel<<<NB2, 1024, 0, stream>>>(ebuf, S, row_ptr, dinv, esrc, n, NB2, E);

    // 2) layer 1
    gemm_rt_h_kernel<128><<<(n + 63) / 64, 256, 0, stream>>>(x, W1, dinv, Ah, n);
    aggregate8h_kernel<true><<<(n + 3) / 4, 256, 0, stream>>>(Ah, row_ptr, esrc, dinv, b1, B, n);

    // 3) layer 2
    gemm_rt_h_kernel<64><<<(n + 63) / 64, 256, 0, stream>>>(B, W2, dinv, Ah, n);
    aggregate8h_kernel<false><<<(n + 3) / 4, 256, 0, stream>>>(Ah, row_ptr, esrc, dinv, b2, out, n);
}

// Round 8
// 199.808 us; speedup vs baseline: 2.1815x; 1.0014x over previous
//
#include <hip/hip_runtime.h>
#include <hip/hip_fp16.h>

// GCN 2-layer forward. CSR via deterministic 2-level bucket sort (256-node
// buckets, no global atomics); pull aggregation = 8-lane group per node
// gathering fp16 hs rows (fp32 accumulate, no cross-group reductions).
// Layer: out[v] = dinv[v]*(hs[v] + sum_{e:dst=v} hs[src_e]) + b,  hs = (x@W)*dinv.

#define C_HID 64
#define NBLK 128          // blocks for hist/scatter passes

static inline size_t alignup(size_t x) { return (x + 255) & ~(size_t)255; }

typedef __attribute__((address_space(3))) unsigned int lds_uint;
typedef __attribute__((address_space(1))) const unsigned int glob_uint;

// ---------- pass A: per-(block,bucket) histogram (bucket = dst>>8) ----------
__global__ __launch_bounds__(256) void hist_kernel(
    const int* __restrict__ dst, int E, int ePer,
    int* __restrict__ S, int nbuck) {
    __shared__ int h[256];
    h[threadIdx.x] = 0;
    __syncthreads();
    int beg = blockIdx.x * ePer, end = min(E, beg + ePer);
    for (int e = beg + threadIdx.x; e < end; e += 256)
        atomicAdd(&h[dst[e] >> 8], 1);
    __syncthreads();
    for (int b = threadIdx.x; b < nbuck; b += 256)
        S[b * NBLK + blockIdx.x] = h[b];
}

// ---------- pass B: exclusive scan of S (bucket-major), in place ----------
__global__ __launch_bounds__(1024) void scan_hist_kernel(int* __restrict__ S, int m) {
    __shared__ int wsum[16];
    int carry = 0;
    const int lane = threadIdx.x & 63, wav = threadIdx.x >> 6;
    for (int base = 0; base < m; base += 1024) {
        int i = base + threadIdx.x;
        int v = (i < m) ? S[i] : 0;
        int s = v;
#pragma unroll
        for (int off = 1; off < 64; off <<= 1) {
            int t = __shfl_up(s, off);
            if (lane >= off) s += t;
        }
        if (lane == 63) wsum[wav] = s;
        __syncthreads();
        if (wav == 0 && lane < 16) {
            int ws = wsum[lane];
#pragma unroll
            for (int off = 1; off < 16; off <<= 1) {
                int t = __shfl_up(ws, off);
                if (lane >= off) ws += t;
            }
            wsum[lane] = ws;
        }
        __syncthreads();
        int chunk_total = wsum[15];
        int excl = carry + (wav ? wsum[wav - 1] : 0) + (s - v);
        if (i < m) S[i] = excl;
        carry += chunk_total;
        __syncthreads();
    }
}

// ---------- pass C: scatter edges into bucket-grouped runs ----------
__global__ __launch_bounds__(256) void bucket_scatter_kernel(
    const int* __restrict__ src, const int* __restrict__ dst, int E, int ePer,
    const int* __restrict__ S, unsigned* __restrict__ ebuf, int nbuck) {
    __shared__ int cur[256];
    int beg = blockIdx.x * ePer, end = min(E, beg + ePer);
    for (int i = threadIdx.x; i < nbuck; i += 256)
        cur[i] = S[i * NBLK + blockIdx.x];
    __syncthreads();
    for (int e = beg + threadIdx.x; e < end; e += 256) {
        int d = dst[e];
        int s = src[e];
        int pos = atomicAdd(&cur[d >> 8], 1);             // LDS atomic
        ebuf[pos] = ((unsigned)s << 8) | (unsigned)(d & 255);
    }
}

// ---------- pass D: per-bucket CSR finalize (196 blocks x 256 thr) ----------
__global__ __launch_bounds__(256) void build_csr_kernel(
    const unsigned* __restrict__ ebuf, const int* __restrict__ S,
    int* __restrict__ row_ptr, float* __restrict__ dinv,
    int* __restrict__ esrc, int n, int nbuck, int E) {
    __shared__ int hist[256];
    __shared__ int wsum[4];
    const int b = blockIdx.x;
    const int node0 = b << 8;
    const int ebeg = S[b * NBLK];
    const int eend = (b + 1 < nbuck) ? S[(b + 1) * NBLK] : E;
    const int lane = threadIdx.x & 63, wav = threadIdx.x >> 6;

    hist[threadIdx.x] = 0;
    __syncthreads();
    for (int e = ebeg + threadIdx.x; e < eend; e += 256)
        atomicAdd(&hist[ebuf[e] & 255], 1);
    __syncthreads();
    int deg = hist[threadIdx.x];

    int s = deg;
#pragma unroll
    for (int off = 1; off < 64; off <<= 1) {
        int t = __shfl_up(s, off);
        if (lane >= off) s += t;
    }
    if (lane == 63) wsum[wav] = s;
    __syncthreads();
    if (wav == 0 && lane < 4) {
        int ws = wsum[lane];
#pragma unroll
        for (int off = 1; off < 4; off <<= 1) {
            int t = __shfl_up(ws, off);
            if (lane >= off) ws += t;
        }
        wsum[lane] = ws;
    }
    __syncthreads();
    int incl = (wav ? wsum[wav - 1] : 0) + s;
    int excl = incl - deg;
    __syncthreads();
    hist[threadIdx.x] = ebeg + excl;
    int v = node0 + threadIdx.x;
    if (v < n) {
        row_ptr[v + 1] = ebeg + incl;
        dinv[v] = rsqrtf(1.0f + (float)deg);
        if (v == 0) row_ptr[0] = 0;
    }
    __syncthreads();
    for (int e = ebeg + threadIdx.x; e < eend; e += 256) {
        unsigned p = ebuf[e];
        int pos = atomicAdd(&hist[p & 255], 1);           // LDS atomic
        esrc[pos] = (int)(p >> 8);
    }
}

// ---------- register-tiled GEMM, fp16 output ----------
template <int K>
__global__ __launch_bounds__(256) void gemm_rt_h_kernel(
    const float* __restrict__ X, const float* __restrict__ W,
    const float* __restrict__ dinv, __half* __restrict__ outh, int n) {
    constexpr int KP = K + 4;
    __shared__ float Xs[64 * KP];
    __shared__ float Ws[K * 64];
    const int t = threadIdx.x;
    const int lane = t & 63;
    const int wav = t >> 6;
    const int row0 = blockIdx.x * 64;

    {
        const char* gb = (const char*)W;
        char* lb = (char*)Ws;
        for (int off = wav * 1024; off < K * 64 * 4; off += 4096)
            __builtin_amdgcn_global_load_lds((glob_uint*)(gb + off + lane * 16),
                                             (lds_uint*)(lb + off), 16, 0, 0);
    }
    if (row0 + 64 <= n) {
        const float4* g4 = (const float4*)(X + (size_t)row0 * K);
        for (int i = t; i < 64 * (K / 4); i += 256) {
            float4 v = g4[i];
            int r = i / (K / 4), k0 = (i % (K / 4)) * 4;
            *(float4*)&Xs[r * KP + k0] = v;
        }
    } else {
        for (int i = t; i < 64 * K; i += 256) {
            int r = i / K, k = i % K;
            Xs[r * KP + k] = (row0 + r < n) ? X[(size_t)(row0 + r) * K + k] : 0.0f;
        }
    }
    __syncthreads();

    const int tx = t & 15;
    const int ty = t >> 4;
    float acc[4][4] = {{0.f}};

#pragma unroll 2
    for (int k0 = 0; k0 < K; k0 += 4) {
        float4 a0 = *(const float4*)&Xs[(4 * ty + 0) * KP + k0];
        float4 a1 = *(const float4*)&Xs[(4 * ty + 1) * KP + k0];
        float4 a2 = *(const float4*)&Xs[(4 * ty + 2) * KP + k0];
        float4 a3 = *(const float4*)&Xs[(4 * ty + 3) * KP + k0];
        float4 b0 = *(const float4*)&Ws[(k0 + 0) * 64 + 4 * tx];
        float4 b1 = *(const float4*)&Ws[(k0 + 1) * 64 + 4 * tx];
        float4 b2 = *(const float4*)&Ws[(k0 + 2) * 64 + 4 * tx];
        float4 b3 = *(const float4*)&Ws[(k0 + 3) * 64 + 4 * tx];
        const float* ap[4] = {(const float*)&a0, (const float*)&a1,
                              (const float*)&a2, (const float*)&a3};
        const float* bp[4] = {(const float*)&b0, (const float*)&b1,
                              (const float*)&b2, (const float*)&b3};
#pragma unroll
        for (int r = 0; r < 4; ++r)
#pragma unroll
            for (int kk = 0; kk < 4; ++kk) {
                float av = ap[r][kk];
#pragma unroll
                for (int c = 0; c < 4; ++c)
                    acc[r][c] = fmaf(av, bp[kk][c], acc[r][c]);
            }
    }

#pragma unroll
    for (int r = 0; r < 4; ++r) {
        int row = row0 + 4 * ty + r;
        if (row < n) {
            float dv = dinv[row];
            __half2 p01 = __floats2half2_rn(acc[r][0] * dv, acc[r][1] * dv);
            __half2 p23 = __floats2half2_rn(acc[r][2] * dv, acc[r][3] * dv);
            float2 st;
            ((__half2*)&st)[0] = p01;
            ((__half2*)&st)[1] = p23;
            *(float2*)&outh[(size_t)row * 64 + 4 * tx] = st;
        }
    }
}

// ---------- pull aggregation: 8-lane group per node ----------
// Lane c8 of group v owns channels c8*8..c8*8+7 (one 16B fp16 chunk).
// No cross-group shuffles, no per-edge predication; unroll x2 for MLP.
template <bool RELU>
__global__ __launch_bounds__(256) void aggregate_g8_kernel(
    const __half* __restrict__ hs,
    const int* __restrict__ row_ptr,
    const int* __restrict__ esrc,
    const float* __restrict__ dinv,
    const float* __restrict__ bias,
    float* __restrict__ out, int n) {
    const int v = blockIdx.x * 32 + (threadIdx.x >> 3);
    if (v >= n) return;
    const int c8 = threadIdx.x & 7;
    const float4* __restrict__ hs4 = (const float4*)hs;   // row = 8 float4s

    const int beg = row_ptr[v];
    const int end = row_ptr[v + 1];

    float acc[8];
    {   // self-loop term
        float4 raw = hs4[(size_t)v * 8 + c8];
        const __half2* hp = (const __half2*)&raw;
#pragma unroll
        for (int q = 0; q < 4; ++q) {
            float2 f = __half22float2(hp[q]);
            acc[2 * q] = f.x; acc[2 * q + 1] = f.y;
        }
    }

    int j = beg;
    for (; j + 2 <= end; j += 2) {
        int s0 = esrc[j];
        int s1 = esrc[j + 1];
        float4 r0 = hs4[(size_t)s0 * 8 + c8];
        float4 r1 = hs4[(size_t)s1 * 8 + c8];
        const __half2* h0 = (const __half2*)&r0;
        const __half2* h1 = (const __half2*)&r1;
#pragma unroll
        for (int q = 0; q < 4; ++q) {
            float2 f0 = __half22float2(h0[q]);
            float2 f1 = __half22float2(h1[q]);
            acc[2 * q]     += f0.x + f1.x;
            acc[2 * q + 1] += f0.y + f1.y;
        }
    }
    if (j < end) {
        int s0 = esrc[j];
        float4 r0 = hs4[(size_t)s0 * 8 + c8];
        const __half2* h0 = (const __half2*)&r0;
#pragma unroll
        for (int q = 0; q < 4; ++q) {
            float2 f0 = __half22float2(h0[q]);
            acc[2 * q]     += f0.x;
            acc[2 * q + 1] += f0.y;
        }
    }

    float dv = dinv[v];
    float4 b0 = *(const float4*)(bias + c8 * 8);
    float4 b1 = *(const float4*)(bias + c8 * 8 + 4);
    float4 o0, o1;
    o0.x = acc[0] * dv + b0.x; o0.y = acc[1] * dv + b0.y;
    o0.z = acc[2] * dv + b0.z; o0.w = acc[3] * dv + b0.w;
    o1.x = acc[4] * dv + b1.x; o1.y = acc[5] * dv + b1.y;
    o1.z = acc[6] * dv + b1.z; o1.w = acc[7] * dv + b1.w;
    if (RELU) {
        o0.x = fmaxf(o0.x, 0.f); o0.y = fmaxf(o0.y, 0.f);
        o0.z = fmaxf(o0.z, 0.f); o0.w = fmaxf(o0.w, 0.f);
        o1.x = fmaxf(o1.x, 0.f); o1.y = fmaxf(o1.y, 0.f);
        o1.z = fmaxf(o1.z, 0.f); o1.w = fmaxf(o1.w, 0.f);
    }
    float4* op = (float4*)(out + (size_t)v * 64 + c8 * 8);
    op[0] = o0;
    op[1] = o1;
}

extern "C" void kernel_launch(void* const* d_in, const int* in_sizes, int n_in,
                              void* d_out, int out_size, void* d_ws, size_t ws_size,
                              hipStream_t stream) {
    const float* x  = (const float*)d_in[0];
    const int*   ei = (const int*)d_in[1];
    const float* W1 = (const float*)d_in[2];
    const float* b1 = (const float*)d_in[3];
    const float* W2 = (const float*)d_in[4];
    const float* b2 = (const float*)d_in[5];
    float* out = (float*)d_out;

    const int C_IN = 128;
    const int n = in_sizes[0] / C_IN;   // 50000 (must be <= 65536 for 8-bit dlocal pack)
    const int E = in_sizes[1] / 2;      // 800000
    const int* src = ei;
    const int* dst = ei + E;

    // Workspace: dinv | Ah (fp16) | B (f32) | row_ptr | S | ebuf | esrc  (~27 MB)
    char* w = (char*)d_ws;
    float*    dinv    = (float*)w;    w += alignup((size_t)n * sizeof(float));
    __half*   Ah      = (__half*)w;   w += alignup((size_t)n * C_HID * sizeof(__half));
    float*    B       = (float*)w;    w += alignup((size_t)n * C_HID * sizeof(float));
    int*      row_ptr = (int*)w;      w += alignup((size_t)(n + 1) * sizeof(int));
    int*      S       = (int*)w;      w += alignup((size_t)256 * NBLK * sizeof(int));
    unsigned* ebuf    = (unsigned*)w; w += alignup((size_t)E * sizeof(unsigned));
    int*      esrc    = (int*)w;

    const int NB2 = (n + 255) >> 8;             // 196 buckets (needs n <= 65536)
    const int ePer = (E + NBLK - 1) / NBLK;     // edges per block

    // 1) CSR build (no global atomics)
    hist_kernel<<<NBLK, 256, 0, stream>>>(dst, E, ePer, S, NB2);
    scan_hist_kernel<<<1, 1024, 0, stream>>>(S, NB2 * NBLK);
    bucket_scatter_kernel<<<NBLK, 256, 0, stream>>>(src, dst, E, ePer, S, ebuf, NB2);
    build_csr_kernel<<<NB2, 256, 0, stream>>>(ebuf, S, row_ptr, dinv, esrc, n, NB2, E);

    // 2) layer 1
    gemm_rt_h_kernel<128><<<(n + 63) / 64, 256, 0, stream>>>(x, W1, dinv, Ah, n);
    aggregate_g8_kernel<true><<<(n + 31) / 32, 256, 0, stream>>>(Ah, row_ptr, esrc, dinv, b1, B, n);

    // 3) layer 2
    gemm_rt_h_kernel<64><<<(n + 63) / 64, 256, 0, stream>>>(B, W2, dinv, Ah, n);
    aggregate_g8_kernel<false><<<(n + 31) / 32, 256, 0, stream>>>(Ah, row_ptr, esrc, dinv, b2, out, n);
}